// Round 2
// baseline (1869.280 us; speedup 1.0000x reference)
//
#include <hip/hip_runtime.h>

// Fused transformer block, fp32, one thread per (sequence,row).
// t=8 rows/seq live in 8 consecutive lanes of one wave -> wave-synchronous
// K/V exchange via LDS (in-order LDS pipe per wave), no __syncthreads needed.
//
// Round-2 changes vs round-1:
//  - LDS shrunk 65KB -> 17KB: single per-head K/V staging buffer reused
//    across the h-loop (wave-synchronous reuse, no barriers).
//  - seq stride 68 floats: 8 seq-groups/wave map to disjoint bank quads on
//    reads; within a group all 8 lanes broadcast-read the same address.
//  - float4 LDS writes/reads (ds_write_b128 / ds_read_b128).
//  - __launch_bounds__(256,4): cap VGPR at 128 -> 4 waves/SIMD.
//  - softmax without max-subtraction (scores bounded; masked -> 0 directly).

#define SEQ_PB 32
#define THREADS 256
#define KV_STRIDE 68   // 8 rows * 8 d + 4 pad floats; 272 B: 16B-aligned, banks shift 4/seq

__global__ __launch_bounds__(THREADS, 4)
void block_fused(const float* __restrict__ X,
                 const float* __restrict__ Wattn,   // (4,32,24) [h][c][d], d: k=0..7,q=8..15,v=16..23
                 const float* __restrict__ Wproj,   // (32,32)  [cin][cout]
                 const float* __restrict__ Wff1,    // (32,128) [c][j]
                 const float* __restrict__ Wff2,    // (128,32) [j][c]
                 float* __restrict__ Out,
                 int nseq)
{
    __shared__ __align__(16) float sK[SEQ_PB * KV_STRIDE];  // 8704 B
    __shared__ __align__(16) float sV[SEQ_PB * KV_STRIDE];  // 8704 B

    const int tid = threadIdx.x;
    const int s_local = tid >> 3;          // 0..31
    const int t = tid & 7;                 // row within sequence
    const int seq = blockIdx.x * SEQ_PB + s_local;
    if (seq >= nseq) return;               // wave-uniform for the full grid

    const float scale = 0.17677669529663687f;  // 32^-0.5 (full embed dim, per reference)

    // ---- load my row of X (32 floats, 8x float4) ----
    const float* xrow = X + (size_t)seq * 256 + (size_t)t * 32;
    float x[32];
    #pragma unroll
    for (int i = 0; i < 8; ++i) {
        float4 v4 = reinterpret_cast<const float4*>(xrow)[i];
        x[4*i+0] = v4.x; x[4*i+1] = v4.y; x[4*i+2] = v4.z; x[4*i+3] = v4.w;
    }

    // x2 accumulates: x + attn @ Wproj  (proj folded into the head loop)
    float x2[32];
    #pragma unroll
    for (int c = 0; c < 32; ++c) x2[c] = x[c];

    float* kbase = &sK[s_local * KV_STRIDE];
    float* vbase = &sV[s_local * KV_STRIDE];

    // ---- per-head: QKV -> LDS(k,v) -> scores -> softmax -> attn -> +proj ----
    #pragma unroll 1
    for (int h = 0; h < 4; ++h) {
        // qkv for my row, this head: acc[0..7]=k, [8..15]=q, [16..23]=v
        float acc[24];
        #pragma unroll
        for (int d = 0; d < 24; ++d) acc[d] = 0.0f;
        const float* wa = Wattn + h * 768;   // (h*32+c)*24 + d
        #pragma unroll
        for (int c = 0; c < 32; ++c) {
            float xc = x[c];
            #pragma unroll
            for (int d = 0; d < 24; ++d)
                acc[d] = fmaf(xc, wa[c * 24 + d], acc[d]);
        }

        // stash k, v for my row into LDS as float4 (b128), reused per head
        float* kb = kbase + t * 8;
        float* vb = vbase + t * 8;
        reinterpret_cast<float4*>(kb)[0] = make_float4(acc[0],  acc[1],  acc[2],  acc[3]);
        reinterpret_cast<float4*>(kb)[1] = make_float4(acc[4],  acc[5],  acc[6],  acc[7]);
        reinterpret_cast<float4*>(vb)[0] = make_float4(acc[16], acc[17], acc[18], acc[19]);
        reinterpret_cast<float4*>(vb)[1] = make_float4(acc[20], acc[21], acc[22], acc[23]);

        // q, pre-scaled
        float q[8];
        #pragma unroll
        for (int d = 0; d < 8; ++d) q[d] = acc[8 + d] * scale;

        // scores + exp (no max-subtraction: |score| bounded ~0.4)
        float e[8];
        float sum = 0.0f;
        #pragma unroll
        for (int j = 0; j < 8; ++j) {
            const float4* kr = reinterpret_cast<const float4*>(kbase + j * 8);
            float4 ka = kr[0], kb4 = kr[1];
            float dot = q[0] * ka.x;
            dot = fmaf(q[1], ka.y, dot);
            dot = fmaf(q[2], ka.z, dot);
            dot = fmaf(q[3], ka.w, dot);
            dot = fmaf(q[4], kb4.x, dot);
            dot = fmaf(q[5], kb4.y, dot);
            dot = fmaf(q[6], kb4.z, dot);
            dot = fmaf(q[7], kb4.w, dot);
            float ej = (j <= t) ? __expf(dot) : 0.0f;
            e[j] = ej;
            sum += ej;
        }
        float inv = 1.0f / sum;

        // attn_h[d] = sum_j w_j * v_j[d]
        float ad[8];
        #pragma unroll
        for (int d = 0; d < 8; ++d) ad[d] = 0.0f;
        #pragma unroll
        for (int j = 0; j < 8; ++j) {
            float w = e[j];
            const float4* vr = reinterpret_cast<const float4*>(vbase + j * 8);
            float4 va = vr[0], vb4 = vr[1];
            ad[0] = fmaf(w, va.x, ad[0]);
            ad[1] = fmaf(w, va.y, ad[1]);
            ad[2] = fmaf(w, va.z, ad[2]);
            ad[3] = fmaf(w, va.w, ad[3]);
            ad[4] = fmaf(w, vb4.x, ad[4]);
            ad[5] = fmaf(w, vb4.y, ad[5]);
            ad[6] = fmaf(w, vb4.z, ad[6]);
            ad[7] = fmaf(w, vb4.w, ad[7]);
        }

        // fold proj: x2[c] += attn_h[d] * Wproj[h*8+d][c]
        #pragma unroll
        for (int d = 0; d < 8; ++d) {
            float adv = ad[d] * inv;
            const float* wp = Wproj + (h * 8 + d) * 32;
            #pragma unroll
            for (int c = 0; c < 32; ++c)
                x2[c] = fmaf(adv, wp[c], x2[c]);
        }
    }

    // ---- FF: out = x2 + relu(x2 @ Wff1) @ Wff2, hidden in chunks of 8 ----
    float out[32];
    #pragma unroll
    for (int c = 0; c < 32; ++c) out[c] = x2[c];

    #pragma unroll 1
    for (int jb = 0; jb < 16; ++jb) {
        float hacc[8];
        #pragma unroll
        for (int j = 0; j < 8; ++j) hacc[j] = 0.0f;
        #pragma unroll
        for (int c = 0; c < 32; ++c) {
            float xc = x2[c];
            const float* w1 = Wff1 + c * 128 + jb * 8;
            #pragma unroll
            for (int j = 0; j < 8; ++j)
                hacc[j] = fmaf(xc, w1[j], hacc[j]);
        }
        #pragma unroll
        for (int j = 0; j < 8; ++j) {
            float hj = fmaxf(hacc[j], 0.0f);
            const float* w2 = Wff2 + (jb * 8 + j) * 32;
            #pragma unroll
            for (int c = 0; c < 32; ++c)
                out[c] = fmaf(hj, w2[c], out[c]);
        }
    }

    // ---- store ----
    float* orow = Out + (size_t)seq * 256 + (size_t)t * 32;
    #pragma unroll
    for (int i = 0; i < 8; ++i) {
        float4 v4 = make_float4(out[4*i+0], out[4*i+1], out[4*i+2], out[4*i+3]);
        reinterpret_cast<float4*>(orow)[i] = v4;
    }
}

extern "C" void kernel_launch(void* const* d_in, const int* in_sizes, int n_in,
                              void* d_out, int out_size, void* d_ws, size_t ws_size,
                              hipStream_t stream) {
    (void)n_in; (void)out_size; (void)d_ws; (void)ws_size;
    const float* X     = (const float*)d_in[0];
    const float* Wattn = (const float*)d_in[1];
    const float* Wproj = (const float*)d_in[2];
    const float* Wff1  = (const float*)d_in[3];
    const float* Wff2  = (const float*)d_in[4];
    float* Out = (float*)d_out;

    const int nseq = in_sizes[0] / 256;            // (b, 8, 32)
    const int blocks = (nseq + SEQ_PB - 1) / SEQ_PB;
    block_fused<<<dim3(blocks), dim3(THREADS), 0, stream>>>(
        X, Wattn, Wproj, Wff1, Wff2, Out, nseq);
}

// Round 3
// 221.980 us; speedup vs baseline: 8.4209x; 8.4209x over previous
//
#include <hip/hip_runtime.h>

// Fused transformer block in bf16 MFMA (gfx950 16x16x32), fp32 residuals.
// One wave processes M-tiles of 16 seq-rows (= 2 sequences of t=8) end-to-end.
// All staging is wave-private LDS (in-order LDS pipe per wave) -> NO barriers.
//
// Trick: weight GEMMs are computed TRANSPOSED (OUT^T = W^T * ACT^T) with the
// weight as the A-operand (resident VGPR frags, gathered once per wave).
//  - B-frag of ACT^T reads row-major [row][ch] LDS tiles as ds_read_b128.
//  - C^T output: each lane holds 4 consecutive CHANNELS of one seq-row ->
//    2x v_cvt_pk_bf16_f32 + 1x ds_write_b64. Both sides vectorized.
// V is computed in NORMAL orientation so V^T stages cheaply for PV;
// scores are computed as scores^T = K*Q^T so softmax row-sum = 2 shfl_xor.

typedef __attribute__((ext_vector_type(8))) short        bf16x8;
typedef __attribute__((ext_vector_type(4))) float        f32x4;
typedef __attribute__((ext_vector_type(4))) int          i32x4;
typedef __attribute__((ext_vector_type(2))) unsigned int u32x2;

#define THREADS 256
#define TPB 64   // tiles per block
#define TPW 16   // tiles per wave (4 waves)

// per-wave LDS region offsets (bytes); strides padded for bank spread + 16B align
#define LDS_X     0      // [16][40] bf16  stride  80B : X tile,   ch 0..31
#define LDS_QK    1280   // [16][72] bf16  stride 144B : ch = 16h + (k:0..7, q:8..15)
#define LDS_VT    3584   // [32][24] bf16  stride  48B : rows vch=8h+d, cols key
#define LDS_P2    5120   // 2x [16][40]   stride  80B : P tiles, keys 0..15 even head, 16..31 odd
#define LDS_ATTN  7680   // [16][40]       stride  80B
#define LDS_X2    8960   // [16][40]       stride  80B
#define LDS_HID   10240  // [16][136]      stride 272B
#define LDS_OUT   14592  // [16][36] f32   stride 144B
#define LDS_WAVE  16896

__device__ __forceinline__ unsigned pk_bf16(float a, float b) {
    unsigned r;
    asm("v_cvt_pk_bf16_f32 %0, %1, %2" : "=v"(r) : "v"(a), "v"(b));
    return r;
}

union frag_u { i32x4 i; bf16x8 b; };

// A/B-frag gather of a weight matrix column: elem j = p[(8g+j)*ldk]
__device__ __forceinline__ bf16x8 gather_w(const float* p, int ldk, int g) {
    frag_u r;
    #pragma unroll
    for (int jj = 0; jj < 4; ++jj) {
        float a = p[(8 * g + 2 * jj) * ldk];
        float b = p[(8 * g + 2 * jj + 1) * ldk];
        r.i[jj] = (int)pk_bf16(a, b);
    }
    return r.b;
}

__global__ __launch_bounds__(THREADS)
void block_mfma(const float* __restrict__ X,
                const float* __restrict__ Wattn,   // (4,32,24) d: k0..7 q8..15 v16..23
                const float* __restrict__ Wproj,   // (32,32) [in][out]
                const float* __restrict__ Wff1,    // (32,128)
                const float* __restrict__ Wff2,    // (128,32)
                float* __restrict__ Out,
                int ntiles)
{
    __shared__ __align__(16) char smem[4 * LDS_WAVE];

    const int lane = threadIdx.x & 63;
    const int wid  = threadIdx.x >> 6;
    const int g    = lane >> 4;   // k-group / C row-group
    const int c    = lane & 15;   // seq-row (col) for transposed GEMMs
    char* W = smem + wid * LDS_WAVE;

    const float scale = 0.17677669529663687f;  // 32^-0.5 (full embed dim, per ref)
    const f32x4 z4 = {0.f, 0.f, 0.f, 0.f};

    // ---- resident weight fragments (gathered once; ~96 VGPR) ----
    bf16x8 wqk[4], wv[2], wp[2], w1[8], w2[2][4];
    #pragma unroll
    for (int n = 0; n < 4; ++n)          // qk tile n == head n; och d = c (k:0..7,q:8..15)
        wqk[n] = gather_w(Wattn + n * 768 + c, 24, g);
    #pragma unroll
    for (int n = 0; n < 2; ++n) {        // v out-ch = 8h+d
        int vch = 16 * n + c;
        wv[n] = gather_w(Wattn + (vch >> 3) * 768 + 16 + (vch & 7), 24, g);
    }
    #pragma unroll
    for (int n = 0; n < 2; ++n)
        wp[n] = gather_w(Wproj + 16 * n + c, 32, g);
    #pragma unroll
    for (int n = 0; n < 8; ++n)
        w1[n] = gather_w(Wff1 + 16 * n + c, 128, g);
    #pragma unroll
    for (int n = 0; n < 2; ++n)
        #pragma unroll
        for (int ks = 0; ks < 4; ++ks)
            w2[n][ks] = gather_w(Wff2 + ks * 1024 + 16 * n + c, 32, g);

    // ---- per-lane constant masks ----
    float mf[4];                               // causal+same-seq mask (scores^T space)
    #pragma unroll
    for (int r = 0; r < 4; ++r) {
        int key = 4 * g + r;
        mf[r] = ((key >> 3) == (c >> 3) && (key & 7) <= (c & 7)) ? 1.f : 0.f;
    }
    const int mQK = (lane < 16) ? -1 : 0;                                  // zero k-groups g>0
    const int mA  = (((lane >> 3) & 1) == ((lane >> 5) & 1)) ? -1 : 0;     // PV block-diag
    const i32x4 vQK = {mQK, mQK, mQK, mQK};
    const i32x4 vA  = {mA, mA, mA, mA};

    const int tile0 = blockIdx.x * TPB + wid * TPW;

    for (int it = 0; it < TPW; ++it) {
        const int tile = tile0 + it;
        if (tile >= ntiles) break;                      // wave-uniform
        const float* xg = X + (size_t)tile * 512;
        float* outg = Out + (size_t)tile * 512;

        // ---- stage X (16 rows x 32 ch) fp32 -> bf16 LDS ----
        f32x4 xa = *(const f32x4*)(xg + lane * 8);
        f32x4 xb = *(const f32x4*)(xg + lane * 8 + 4);
        // residual X at C^T points: ch = 16n + 4g + r (L1-hit re-reads)
        float rx[2][4];
        #pragma unroll
        for (int n = 0; n < 2; ++n)
            #pragma unroll
            for (int r = 0; r < 4; ++r)
                rx[n][r] = xg[c * 32 + 16 * n + 4 * g + r];

        {
            i32x4 xi = { (int)pk_bf16(xa[0], xa[1]), (int)pk_bf16(xa[2], xa[3]),
                         (int)pk_bf16(xb[0], xb[1]), (int)pk_bf16(xb[2], xb[3]) };
            *(i32x4*)(void*)(W + LDS_X + (lane >> 2) * 80 + (lane & 3) * 16) = xi;
        }

        frag_u xf; xf.i = *(i32x4*)(void*)(W + LDS_X + c * 80 + g * 16);

        // ---- QK^T GEMM (transposed): 4 mfma; C rows = q/k chans, cols = seq-row ----
        #pragma unroll
        for (int n = 0; n < 4; ++n) {
            f32x4 qc = __builtin_amdgcn_mfma_f32_16x16x32_bf16(wqk[n], xf.b, z4, 0, 0, 0);
            u32x2 w64 = { pk_bf16(qc[0], qc[1]), pk_bf16(qc[2], qc[3]) };
            *(u32x2*)(void*)(W + LDS_QK + c * 144 + (16 * n + 4 * g) * 2) = w64;
        }
        // ---- V GEMM (normal): 2 mfma; C rows = keys, cols = vch -> VT[vch][key] ----
        #pragma unroll
        for (int n = 0; n < 2; ++n) {
            f32x4 vc = __builtin_amdgcn_mfma_f32_16x16x32_bf16(xf.b, wv[n], z4, 0, 0, 0);
            u32x2 w64 = { pk_bf16(vc[0], vc[1]), pk_bf16(vc[2], vc[3]) };
            *(u32x2*)(void*)(W + LDS_VT + (16 * n + c) * 48 + 4 * g * 2) = w64;
        }

        // ---- scores^T = K*Q^T, softmax, P -> P2 tiles ----
        #pragma unroll
        for (int h = 0; h < 4; ++h) {
            frag_u kf, qf;
            kf.i = *(i32x4*)(void*)(W + LDS_QK + c * 144 + 32 * h);
            qf.i = *(i32x4*)(void*)(W + LDS_QK + c * 144 + 32 * h + 16);
            kf.i &= vQK; qf.i &= vQK;
            f32x4 sT = __builtin_amdgcn_mfma_f32_16x16x32_bf16(kf.b, qf.b, z4, 0, 0, 0);
            float e0 = __expf(sT[0] * scale) * mf[0];
            float e1 = __expf(sT[1] * scale) * mf[1];
            float e2 = __expf(sT[2] * scale) * mf[2];
            float e3 = __expf(sT[3] * scale) * mf[3];
            float s = (e0 + e1) + (e2 + e3);
            s += __shfl_xor(s, 16);
            s += __shfl_xor(s, 32);
            float rs = 1.0f / s;
            u32x2 w64 = { pk_bf16(e0 * rs, e1 * rs), pk_bf16(e2 * rs, e3 * rs) };
            *(u32x2*)(void*)(W + LDS_P2 + (h >> 1) * 1280 + c * 80 + ((h & 1) * 16 + 4 * g) * 2) = w64;
        }

        // ---- PV (attn^T = blockdiag(V^T) * P^T): 2 mfma over head-pairs ----
        #pragma unroll
        for (int p = 0; p < 2; ++p) {
            frag_u va, pb;
            va.i = *(i32x4*)(void*)(W + LDS_VT + (16 * p + c) * 48 + (g & 1) * 16);
            va.i &= vA;
            pb.i = *(i32x4*)(void*)(W + LDS_P2 + p * 1280 + c * 80 + g * 16);
            f32x4 pv = __builtin_amdgcn_mfma_f32_16x16x32_bf16(va.b, pb.b, z4, 0, 0, 0);
            u32x2 w64 = { pk_bf16(pv[0], pv[1]), pk_bf16(pv[2], pv[3]) };
            *(u32x2*)(void*)(W + LDS_ATTN + c * 80 + (16 * p + 4 * g) * 2) = w64;
        }

        // ---- proj (transposed) + fp32 residual -> x2 ----
        frag_u af; af.i = *(i32x4*)(void*)(W + LDS_ATTN + c * 80 + g * 16);
        f32x4 x2c[2];
        #pragma unroll
        for (int n = 0; n < 2; ++n) {
            f32x4 pc = __builtin_amdgcn_mfma_f32_16x16x32_bf16(wp[n], af.b, z4, 0, 0, 0);
            #pragma unroll
            for (int r = 0; r < 4; ++r) x2c[n][r] = pc[r] + rx[n][r];
            u32x2 w64 = { pk_bf16(x2c[n][0], x2c[n][1]), pk_bf16(x2c[n][2], x2c[n][3]) };
            *(u32x2*)(void*)(W + LDS_X2 + c * 80 + (16 * n + 4 * g) * 2) = w64;
        }

        // ---- FF1 (transposed) + relu -> hidden ----
        frag_u bf; bf.i = *(i32x4*)(void*)(W + LDS_X2 + c * 80 + g * 16);
        #pragma unroll
        for (int n = 0; n < 8; ++n) {
            f32x4 hc = __builtin_amdgcn_mfma_f32_16x16x32_bf16(w1[n], bf.b, z4, 0, 0, 0);
            #pragma unroll
            for (int r = 0; r < 4; ++r) hc[r] = fmaxf(hc[r], 0.f);
            u32x2 w64 = { pk_bf16(hc[0], hc[1]), pk_bf16(hc[2], hc[3]) };
            *(u32x2*)(void*)(W + LDS_HID + c * 272 + (16 * n + 4 * g) * 2) = w64;
        }

        // ---- FF2 (transposed, K=128) accumulating onto x2 (fp32 residual) ----
        frag_u hf0, hf1, hf2, hf3;
        hf0.i = *(i32x4*)(void*)(W + LDS_HID + c * 272 + 0 * 64 + g * 16);
        hf1.i = *(i32x4*)(void*)(W + LDS_HID + c * 272 + 1 * 64 + g * 16);
        hf2.i = *(i32x4*)(void*)(W + LDS_HID + c * 272 + 2 * 64 + g * 16);
        hf3.i = *(i32x4*)(void*)(W + LDS_HID + c * 272 + 3 * 64 + g * 16);
        #pragma unroll
        for (int n = 0; n < 2; ++n) {
            f32x4 oc = x2c[n];
            oc = __builtin_amdgcn_mfma_f32_16x16x32_bf16(w2[n][0], hf0.b, oc, 0, 0, 0);
            oc = __builtin_amdgcn_mfma_f32_16x16x32_bf16(w2[n][1], hf1.b, oc, 0, 0, 0);
            oc = __builtin_amdgcn_mfma_f32_16x16x32_bf16(w2[n][2], hf2.b, oc, 0, 0, 0);
            oc = __builtin_amdgcn_mfma_f32_16x16x32_bf16(w2[n][3], hf3.b, oc, 0, 0, 0);
            *(f32x4*)(void*)(W + LDS_OUT + c * 144 + (16 * n + 4 * g) * 4) = oc;
        }

        // ---- transpose out^T -> row-major via LDS, coalesced fp32 store ----
        f32x4 r0 = *(f32x4*)(void*)(W + LDS_OUT + (lane >> 2) * 144 + (lane & 3) * 32);
        f32x4 r1 = *(f32x4*)(void*)(W + LDS_OUT + (lane >> 2) * 144 + (lane & 3) * 32 + 16);
        *(f32x4*)(outg + lane * 8)     = r0;
        *(f32x4*)(outg + lane * 8 + 4) = r1;
    }
}

extern "C" void kernel_launch(void* const* d_in, const int* in_sizes, int n_in,
                              void* d_out, int out_size, void* d_ws, size_t ws_size,
                              hipStream_t stream) {
    (void)n_in; (void)out_size; (void)d_ws; (void)ws_size;
    const float* X     = (const float*)d_in[0];
    const float* Wattn = (const float*)d_in[1];
    const float* Wproj = (const float*)d_in[2];
    const float* Wff1  = (const float*)d_in[3];
    const float* Wff2  = (const float*)d_in[4];
    float* Out = (float*)d_out;

    const int nseq   = in_sizes[0] / 256;   // (b, 8, 32)
    const int ntiles = nseq / 2;            // 16 rows per tile
    const int blocks = (ntiles + TPB - 1) / TPB;
    block_mfma<<<dim3(blocks), dim3(THREADS), 0, stream>>>(
        X, Wattn, Wproj, Wff1, Wff2, Out, ntiles);
}

// Round 4
// 214.226 us; speedup vs baseline: 8.7257x; 1.0362x over previous
//
#include <hip/hip_runtime.h>

// Fused transformer block in bf16 MFMA (gfx950 16x16x32), fp32 residuals.
// One wave processes M-tiles of 16 seq-rows (= 2 sequences of t=8) end-to-end.
// All staging is wave-private LDS (in-order LDS pipe per wave) -> NO barriers.
//
// Round-4 changes vs round-3 (dataflow identical):
//  - LDS regions phase-aliased: 16.9KB -> 7.68KB per wave (30.7KB/block),
//    lifting the 2-blocks/CU LDS cap (occupancy was 22%).
//  - next-tile X prefetched across iterations (global latency off the chain).
//  - tile loop kept rolled (#pragma unroll 1).

typedef __attribute__((ext_vector_type(8))) short        bf16x8;
typedef __attribute__((ext_vector_type(4))) float        f32x4;
typedef __attribute__((ext_vector_type(4))) int          i32x4;
typedef __attribute__((ext_vector_type(2))) unsigned int u32x2;

#define THREADS 256
#define TPB 64   // tiles per block
#define TPW 16   // tiles per wave (4 waves)

// per-wave LDS region offsets (bytes), PHASE-ALIASED. Lifetimes:
//  P1 stage/QKV: X,QK,VT   P2 scores: QK,VT,P2   P3 PV: VT,P2,ATTN
//  P4 proj: ATTN,X2        P5 FF1: X2,HID        P6 FF2/store: HID,OUT
#define LDS_X     0      // [16][40] bf16 (1280B)  P1
#define LDS_QK    1280   // [16][72] bf16 (2304B)  P1-P2
#define LDS_VT    3584   // [32][24] bf16 (1536B)  P1-P3
#define LDS_P2    5120   // 2x[16][40] bf16 (2560) P2-P3
#define LDS_ATTN  0      // [16][40] (1280B)       P3-P4  (over X)
#define LDS_X2    1280   // [16][40] (1280B)       P4-P5  (over QK)
#define LDS_HID   2560   // [16][136] (4352B)      P5-P6  (over QK/VT/P2)
#define LDS_OUT   0      // [16][36] f32 (2304B)   P6     (over ATTN/X2)
#define LDS_WAVE  7680

__device__ __forceinline__ unsigned pk_bf16(float a, float b) {
    unsigned r;
    asm("v_cvt_pk_bf16_f32 %0, %1, %2" : "=v"(r) : "v"(a), "v"(b));
    return r;
}

union frag_u { i32x4 i; bf16x8 b; };

// A/B-frag gather of a weight matrix column: elem j = p[(8g+j)*ldk]
__device__ __forceinline__ bf16x8 gather_w(const float* p, int ldk, int g) {
    frag_u r;
    #pragma unroll
    for (int jj = 0; jj < 4; ++jj) {
        float a = p[(8 * g + 2 * jj) * ldk];
        float b = p[(8 * g + 2 * jj + 1) * ldk];
        r.i[jj] = (int)pk_bf16(a, b);
    }
    return r.b;
}

__global__ __launch_bounds__(THREADS)
void block_mfma(const float* __restrict__ X,
                const float* __restrict__ Wattn,   // (4,32,24) d: k0..7 q8..15 v16..23
                const float* __restrict__ Wproj,   // (32,32) [in][out]
                const float* __restrict__ Wff1,    // (32,128)
                const float* __restrict__ Wff2,    // (128,32)
                float* __restrict__ Out,
                int ntiles)
{
    __shared__ __align__(16) char smem[4 * LDS_WAVE];

    const int lane = threadIdx.x & 63;
    const int wid  = threadIdx.x >> 6;
    const int g    = lane >> 4;   // k-group / C row-group
    const int c    = lane & 15;   // seq-row (col) for transposed GEMMs
    char* W = smem + wid * LDS_WAVE;

    const float scale = 0.17677669529663687f;  // 32^-0.5 (full embed dim, per ref)
    const f32x4 z4 = {0.f, 0.f, 0.f, 0.f};

    // ---- resident weight fragments (gathered once; ~96 VGPR) ----
    bf16x8 wqk[4], wv[2], wp[2], w1[8], w2[2][4];
    #pragma unroll
    for (int n = 0; n < 4; ++n)          // qk tile n == head n; och d = c (k:0..7,q:8..15)
        wqk[n] = gather_w(Wattn + n * 768 + c, 24, g);
    #pragma unroll
    for (int n = 0; n < 2; ++n) {        // v out-ch = 8h+d
        int vch = 16 * n + c;
        wv[n] = gather_w(Wattn + (vch >> 3) * 768 + 16 + (vch & 7), 24, g);
    }
    #pragma unroll
    for (int n = 0; n < 2; ++n)
        wp[n] = gather_w(Wproj + 16 * n + c, 32, g);
    #pragma unroll
    for (int n = 0; n < 8; ++n)
        w1[n] = gather_w(Wff1 + 16 * n + c, 128, g);
    #pragma unroll
    for (int n = 0; n < 2; ++n)
        #pragma unroll
        for (int ks = 0; ks < 4; ++ks)
            w2[n][ks] = gather_w(Wff2 + ks * 1024 + 16 * n + c, 32, g);

    // ---- per-lane constant masks ----
    float mf[4];                               // causal+same-seq mask (scores^T space)
    #pragma unroll
    for (int r = 0; r < 4; ++r) {
        int key = 4 * g + r;
        mf[r] = ((key >> 3) == (c >> 3) && (key & 7) <= (c & 7)) ? 1.f : 0.f;
    }
    const int mQK = (lane < 16) ? -1 : 0;                                  // zero k-groups g>0
    const int mA  = (((lane >> 3) & 1) == ((lane >> 5) & 1)) ? -1 : 0;     // PV block-diag
    const i32x4 vQK = {mQK, mQK, mQK, mQK};
    const i32x4 vA  = {mA, mA, mA, mA};

    const int tile0 = blockIdx.x * TPB + wid * TPW;

    // ---- prefetch tile0's X ----
    const float* xg0 = X + (size_t)tile0 * 512;
    f32x4 xa = *(const f32x4*)(xg0 + lane * 8);
    f32x4 xb = *(const f32x4*)(xg0 + lane * 8 + 4);

    #pragma unroll 1
    for (int it = 0; it < TPW; ++it) {
        const int tile = tile0 + it;
        if (tile >= ntiles) break;                      // wave-uniform
        const float* xgc = X + (size_t)tile * 512;
        float* outg = Out + (size_t)tile * 512;

        // residual X at C^T points (used in P4; latency covered by P1-P3)
        f32x4 rx0 = *(const f32x4*)(xgc + c * 32 + 4 * g);
        f32x4 rx1 = *(const f32x4*)(xgc + c * 32 + 16 + 4 * g);

        // ---- stage current X (16 rows x 32 ch) fp32 -> bf16 LDS ----
        {
            i32x4 xi = { (int)pk_bf16(xa[0], xa[1]), (int)pk_bf16(xa[2], xa[3]),
                         (int)pk_bf16(xb[0], xb[1]), (int)pk_bf16(xb[2], xb[3]) };
            *(i32x4*)(void*)(W + LDS_X + (lane >> 2) * 80 + (lane & 3) * 16) = xi;
        }

        // ---- prefetch next tile's X (lands during this tile's compute) ----
        {
            const int tn = (it + 1 < TPW && tile + 1 < ntiles) ? tile + 1 : tile;
            const float* xgn = X + (size_t)tn * 512;
            xa = *(const f32x4*)(xgn + lane * 8);
            xb = *(const f32x4*)(xgn + lane * 8 + 4);
        }

        frag_u xf; xf.i = *(i32x4*)(void*)(W + LDS_X + c * 80 + g * 16);

        // ---- QK^T GEMM (transposed): 4 mfma; C rows = q/k chans, cols = seq-row ----
        #pragma unroll
        for (int n = 0; n < 4; ++n) {
            f32x4 qc = __builtin_amdgcn_mfma_f32_16x16x32_bf16(wqk[n], xf.b, z4, 0, 0, 0);
            u32x2 w64 = { pk_bf16(qc[0], qc[1]), pk_bf16(qc[2], qc[3]) };
            *(u32x2*)(void*)(W + LDS_QK + c * 144 + (16 * n + 4 * g) * 2) = w64;
        }
        // ---- V GEMM (normal): 2 mfma; C rows = keys, cols = vch -> VT[vch][key] ----
        #pragma unroll
        for (int n = 0; n < 2; ++n) {
            f32x4 vc = __builtin_amdgcn_mfma_f32_16x16x32_bf16(xf.b, wv[n], z4, 0, 0, 0);
            u32x2 w64 = { pk_bf16(vc[0], vc[1]), pk_bf16(vc[2], vc[3]) };
            *(u32x2*)(void*)(W + LDS_VT + (16 * n + c) * 48 + 4 * g * 2) = w64;
        }

        // ---- scores^T = K*Q^T, softmax, P -> P2 tiles ----
        #pragma unroll
        for (int h = 0; h < 4; ++h) {
            frag_u kf, qf;
            kf.i = *(i32x4*)(void*)(W + LDS_QK + c * 144 + 32 * h);
            qf.i = *(i32x4*)(void*)(W + LDS_QK + c * 144 + 32 * h + 16);
            kf.i &= vQK; qf.i &= vQK;
            f32x4 sT = __builtin_amdgcn_mfma_f32_16x16x32_bf16(kf.b, qf.b, z4, 0, 0, 0);
            float e0 = __expf(sT[0] * scale) * mf[0];
            float e1 = __expf(sT[1] * scale) * mf[1];
            float e2 = __expf(sT[2] * scale) * mf[2];
            float e3 = __expf(sT[3] * scale) * mf[3];
            float s = (e0 + e1) + (e2 + e3);
            s += __shfl_xor(s, 16);
            s += __shfl_xor(s, 32);
            float rs = 1.0f / s;
            u32x2 w64 = { pk_bf16(e0 * rs, e1 * rs), pk_bf16(e2 * rs, e3 * rs) };
            *(u32x2*)(void*)(W + LDS_P2 + (h >> 1) * 1280 + c * 80 + ((h & 1) * 16 + 4 * g) * 2) = w64;
        }

        // ---- PV (attn^T = blockdiag(V^T) * P^T): 2 mfma over head-pairs ----
        #pragma unroll
        for (int p = 0; p < 2; ++p) {
            frag_u va, pb;
            va.i = *(i32x4*)(void*)(W + LDS_VT + (16 * p + c) * 48 + (g & 1) * 16);
            va.i &= vA;
            pb.i = *(i32x4*)(void*)(W + LDS_P2 + p * 1280 + c * 80 + g * 16);
            f32x4 pv = __builtin_amdgcn_mfma_f32_16x16x32_bf16(va.b, pb.b, z4, 0, 0, 0);
            u32x2 w64 = { pk_bf16(pv[0], pv[1]), pk_bf16(pv[2], pv[3]) };
            *(u32x2*)(void*)(W + LDS_ATTN + c * 80 + (16 * p + 4 * g) * 2) = w64;
        }

        // ---- proj (transposed) + fp32 residual -> x2 ----
        frag_u af; af.i = *(i32x4*)(void*)(W + LDS_ATTN + c * 80 + g * 16);
        f32x4 x2c[2];
        #pragma unroll
        for (int n = 0; n < 2; ++n) {
            f32x4 pc = __builtin_amdgcn_mfma_f32_16x16x32_bf16(wp[n], af.b, z4, 0, 0, 0);
            f32x4 rx = (n == 0) ? rx0 : rx1;
            #pragma unroll
            for (int r = 0; r < 4; ++r) x2c[n][r] = pc[r] + rx[r];
            u32x2 w64 = { pk_bf16(x2c[n][0], x2c[n][1]), pk_bf16(x2c[n][2], x2c[n][3]) };
            *(u32x2*)(void*)(W + LDS_X2 + c * 80 + (16 * n + 4 * g) * 2) = w64;
        }

        // ---- FF1 (transposed) + relu -> hidden ----
        frag_u bf; bf.i = *(i32x4*)(void*)(W + LDS_X2 + c * 80 + g * 16);
        #pragma unroll
        for (int n = 0; n < 8; ++n) {
            f32x4 hc = __builtin_amdgcn_mfma_f32_16x16x32_bf16(w1[n], bf.b, z4, 0, 0, 0);
            #pragma unroll
            for (int r = 0; r < 4; ++r) hc[r] = fmaxf(hc[r], 0.f);
            u32x2 w64 = { pk_bf16(hc[0], hc[1]), pk_bf16(hc[2], hc[3]) };
            *(u32x2*)(void*)(W + LDS_HID + c * 272 + (16 * n + 4 * g) * 2) = w64;
        }

        // ---- FF2 (transposed, K=128) accumulating onto x2 (fp32 residual) ----
        frag_u hf0, hf1, hf2, hf3;
        hf0.i = *(i32x4*)(void*)(W + LDS_HID + c * 272 + 0 * 64 + g * 16);
        hf1.i = *(i32x4*)(void*)(W + LDS_HID + c * 272 + 1 * 64 + g * 16);
        hf2.i = *(i32x4*)(void*)(W + LDS_HID + c * 272 + 2 * 64 + g * 16);
        hf3.i = *(i32x4*)(void*)(W + LDS_HID + c * 272 + 3 * 64 + g * 16);
        #pragma unroll
        for (int n = 0; n < 2; ++n) {
            f32x4 oc = x2c[n];
            oc = __builtin_amdgcn_mfma_f32_16x16x32_bf16(w2[n][0], hf0.b, oc, 0, 0, 0);
            oc = __builtin_amdgcn_mfma_f32_16x16x32_bf16(w2[n][1], hf1.b, oc, 0, 0, 0);
            oc = __builtin_amdgcn_mfma_f32_16x16x32_bf16(w2[n][2], hf2.b, oc, 0, 0, 0);
            oc = __builtin_amdgcn_mfma_f32_16x16x32_bf16(w2[n][3], hf3.b, oc, 0, 0, 0);
            *(f32x4*)(void*)(W + LDS_OUT + c * 144 + (16 * n + 4 * g) * 4) = oc;
        }

        // ---- transpose out^T -> row-major via LDS, coalesced fp32 store ----
        f32x4 r0 = *(f32x4*)(void*)(W + LDS_OUT + (lane >> 2) * 144 + (lane & 3) * 32);
        f32x4 r1 = *(f32x4*)(void*)(W + LDS_OUT + (lane >> 2) * 144 + (lane & 3) * 32 + 16);
        *(f32x4*)(outg + lane * 8)     = r0;
        *(f32x4*)(outg + lane * 8 + 4) = r1;
    }
}

extern "C" void kernel_launch(void* const* d_in, const int* in_sizes, int n_in,
                              void* d_out, int out_size, void* d_ws, size_t ws_size,
                              hipStream_t stream) {
    (void)n_in; (void)out_size; (void)d_ws; (void)ws_size;
    const float* X     = (const float*)d_in[0];
    const float* Wattn = (const float*)d_in[1];
    const float* Wproj = (const float*)d_in[2];
    const float* Wff1  = (const float*)d_in[3];
    const float* Wff2  = (const float*)d_in[4];
    float* Out = (float*)d_out;

    const int nseq   = in_sizes[0] / 256;   // (b, 8, 32)
    const int ntiles = nseq / 2;            // 16 rows per tile
    const int blocks = (ntiles + TPB - 1) / TPB;
    block_mfma<<<dim3(blocks), dim3(THREADS), 0, stream>>>(
        X, Wattn, Wproj, Wff1, Wff2, Out, ntiles);
}

// Round 5
// 186.823 us; speedup vs baseline: 10.0056x; 1.1467x over previous
//
#include <hip/hip_runtime.h>

// Fused transformer block in bf16 MFMA (gfx950 16x16x32), fp32 residuals.
// One wave processes M-tiles of 16 seq-rows (= 2 sequences of t=8) end-to-end.
// All staging is wave-private LDS (in-order LDS pipe per wave) -> NO barriers.
//
// Round-5 changes vs round-4 (math identical):
//  - TWO tiles in flight per wave (phases interleaved A,B in one block,
//    disjoint LDS contexts): occupancy is register-capped at ~2 waves/SIMD
//    (108 arch VGPR + ~104 AGPR weight frags), so buy ILP instead of TLP.
//  - HID stride 272 -> 304 B (272 = 16 banks mod 32 -> 8-way conflict; 304
//    = 12 banks -> 2-way = free). Was ~19M conflict cycles.
//  - sqrt(scale*log2e) folded into Q/K weight frags; exp2 + rcp intrinsics.

typedef __attribute__((ext_vector_type(8))) short        bf16x8;
typedef __attribute__((ext_vector_type(4))) float        f32x4;
typedef __attribute__((ext_vector_type(4))) int          i32x4;
typedef __attribute__((ext_vector_type(2))) unsigned int u32x2;

#define THREADS 256
#define TPB 64   // tiles per block
#define TPW 16   // tiles per wave (4 waves)

// per-context LDS offsets (bytes), PHASE-ALIASED (lifetimes disjoint):
#define LDS_X     0      // [16][40] bf16 (1280B)   P1
#define LDS_QK    1280   // [16][72] bf16 (2304B)   P1-P2
#define LDS_VT    3584   // [32][24] bf16 (1536B)   P1-P3
#define LDS_P2    5120   // 2x[16][40] bf16 (2560B) P2-P3
#define LDS_ATTN  0      // [16][40] (1280B)        P3-P4  (over X)
#define LDS_X2    1280   // [16][40] (1280B)        P4-P5  (over QK)
#define LDS_HID   2560   // [16][152] (4864B)       P5-P6  (stride 304!)
#define LDS_OUT   0      // [16][36] f32 (2304B)    P6     (over ATTN/X2)
#define LDS_CTX   7680

__device__ __forceinline__ unsigned pk_bf16(float a, float b) {
    unsigned r;
    asm("v_cvt_pk_bf16_f32 %0, %1, %2" : "=v"(r) : "v"(a), "v"(b));
    return r;
}

union frag_u { i32x4 i; bf16x8 b; };

// A/B-frag gather of a weight matrix column: elem j = p[(8g+j)*ldk] * s
__device__ __forceinline__ bf16x8 gather_w(const float* p, int ldk, int g, float s) {
    frag_u r;
    #pragma unroll
    for (int jj = 0; jj < 4; ++jj) {
        float a = p[(8 * g + 2 * jj) * ldk] * s;
        float b = p[(8 * g + 2 * jj + 1) * ldk] * s;
        r.i[jj] = (int)pk_bf16(a, b);
    }
    return r.b;
}

// ---------------- phase functions (all offsets compile-time) ----------------

__device__ __forceinline__ void ph_stage(char* Wc, int lane, const f32x4& xa, const f32x4& xb) {
    i32x4 xi = { (int)pk_bf16(xa[0], xa[1]), (int)pk_bf16(xa[2], xa[3]),
                 (int)pk_bf16(xb[0], xb[1]), (int)pk_bf16(xb[2], xb[3]) };
    *(i32x4*)(void*)(Wc + LDS_X + (lane >> 2) * 80 + (lane & 3) * 16) = xi;
}

__device__ __forceinline__ void ph_qkv(char* Wc, int c, int g,
                                       const bf16x8 (&wqk)[4], const bf16x8 (&wv)[2]) {
    const f32x4 z4 = {0.f, 0.f, 0.f, 0.f};
    frag_u xf; xf.i = *(i32x4*)(void*)(Wc + LDS_X + c * 80 + g * 16);
    #pragma unroll
    for (int n = 0; n < 4; ++n) {
        f32x4 qc = __builtin_amdgcn_mfma_f32_16x16x32_bf16(wqk[n], xf.b, z4, 0, 0, 0);
        u32x2 w64 = { pk_bf16(qc[0], qc[1]), pk_bf16(qc[2], qc[3]) };
        *(u32x2*)(void*)(Wc + LDS_QK + c * 144 + (16 * n + 4 * g) * 2) = w64;
    }
    #pragma unroll
    for (int n = 0; n < 2; ++n) {
        f32x4 vc = __builtin_amdgcn_mfma_f32_16x16x32_bf16(xf.b, wv[n], z4, 0, 0, 0);
        u32x2 w64 = { pk_bf16(vc[0], vc[1]), pk_bf16(vc[2], vc[3]) };
        *(u32x2*)(void*)(Wc + LDS_VT + (16 * n + c) * 48 + 8 * g) = w64;
    }
}

__device__ __forceinline__ void ph_scores(char* Wc, int c, int g,
                                          const f32x4& mf, const i32x4& mQK) {
    const f32x4 z4 = {0.f, 0.f, 0.f, 0.f};
    #pragma unroll
    for (int h = 0; h < 4; ++h) {
        frag_u kf, qf;
        kf.i = *(i32x4*)(void*)(Wc + LDS_QK + c * 144 + 32 * h);
        qf.i = *(i32x4*)(void*)(Wc + LDS_QK + c * 144 + 32 * h + 16);
        kf.i &= mQK; qf.i &= mQK;
        f32x4 sT = __builtin_amdgcn_mfma_f32_16x16x32_bf16(kf.b, qf.b, z4, 0, 0, 0);
        // scale*log2e pre-folded (sqrt each into k,q weights) -> raw exp2
        float e0 = __builtin_amdgcn_exp2f(sT[0]) * mf[0];
        float e1 = __builtin_amdgcn_exp2f(sT[1]) * mf[1];
        float e2 = __builtin_amdgcn_exp2f(sT[2]) * mf[2];
        float e3 = __builtin_amdgcn_exp2f(sT[3]) * mf[3];
        float s = (e0 + e1) + (e2 + e3);
        s += __shfl_xor(s, 16);
        s += __shfl_xor(s, 32);
        float rs = __builtin_amdgcn_rcpf(s);
        u32x2 w64 = { pk_bf16(e0 * rs, e1 * rs), pk_bf16(e2 * rs, e3 * rs) };
        *(u32x2*)(void*)(Wc + LDS_P2 + (h >> 1) * 1280 + c * 80 + ((h & 1) * 16 + 4 * g) * 2) = w64;
    }
}

__device__ __forceinline__ void ph_pv(char* Wc, int c, int g, const i32x4& mPV) {
    const f32x4 z4 = {0.f, 0.f, 0.f, 0.f};
    #pragma unroll
    for (int p = 0; p < 2; ++p) {
        frag_u va, pb;
        va.i = *(i32x4*)(void*)(Wc + LDS_VT + (16 * p + c) * 48 + (g & 1) * 16);
        va.i &= mPV;
        pb.i = *(i32x4*)(void*)(Wc + LDS_P2 + p * 1280 + c * 80 + g * 16);
        f32x4 pv = __builtin_amdgcn_mfma_f32_16x16x32_bf16(va.b, pb.b, z4, 0, 0, 0);
        u32x2 w64 = { pk_bf16(pv[0], pv[1]), pk_bf16(pv[2], pv[3]) };
        *(u32x2*)(void*)(Wc + LDS_ATTN + c * 80 + (16 * p + 4 * g) * 2) = w64;
    }
}

__device__ __forceinline__ void ph_proj(char* Wc, int c, int g, const bf16x8 (&wp)[2],
                                        const f32x4& rx0, const f32x4& rx1, f32x4 (&x2c)[2]) {
    frag_u af; af.i = *(i32x4*)(void*)(Wc + LDS_ATTN + c * 80 + g * 16);
    #pragma unroll
    for (int n = 0; n < 2; ++n) {
        const f32x4 z4 = {0.f, 0.f, 0.f, 0.f};
        f32x4 pc = __builtin_amdgcn_mfma_f32_16x16x32_bf16(wp[n], af.b, z4, 0, 0, 0);
        f32x4 rx = (n == 0) ? rx0 : rx1;
        #pragma unroll
        for (int r = 0; r < 4; ++r) x2c[n][r] = pc[r] + rx[r];
        u32x2 w64 = { pk_bf16(x2c[n][0], x2c[n][1]), pk_bf16(x2c[n][2], x2c[n][3]) };
        *(u32x2*)(void*)(Wc + LDS_X2 + c * 80 + (16 * n + 4 * g) * 2) = w64;
    }
}

__device__ __forceinline__ void ph_ff1(char* Wc, int c, int g, const bf16x8 (&w1)[8]) {
    frag_u bf; bf.i = *(i32x4*)(void*)(Wc + LDS_X2 + c * 80 + g * 16);
    #pragma unroll
    for (int n = 0; n < 8; ++n) {
        const f32x4 z4 = {0.f, 0.f, 0.f, 0.f};
        f32x4 hc = __builtin_amdgcn_mfma_f32_16x16x32_bf16(w1[n], bf.b, z4, 0, 0, 0);
        #pragma unroll
        for (int r = 0; r < 4; ++r) hc[r] = fmaxf(hc[r], 0.f);
        u32x2 w64 = { pk_bf16(hc[0], hc[1]), pk_bf16(hc[2], hc[3]) };
        *(u32x2*)(void*)(Wc + LDS_HID + c * 304 + (16 * n + 4 * g) * 2) = w64;
    }
}

__device__ __forceinline__ void ph_ff2(char* Wc, int c, int g,
                                       const bf16x8 (&w2)[2][4], const f32x4 (&x2c)[2]) {
    frag_u hf0, hf1, hf2, hf3;
    hf0.i = *(i32x4*)(void*)(Wc + LDS_HID + c * 304 + 0 * 64 + g * 16);
    hf1.i = *(i32x4*)(void*)(Wc + LDS_HID + c * 304 + 1 * 64 + g * 16);
    hf2.i = *(i32x4*)(void*)(Wc + LDS_HID + c * 304 + 2 * 64 + g * 16);
    hf3.i = *(i32x4*)(void*)(Wc + LDS_HID + c * 304 + 3 * 64 + g * 16);
    #pragma unroll
    for (int n = 0; n < 2; ++n) {
        f32x4 oc = x2c[n];
        oc = __builtin_amdgcn_mfma_f32_16x16x32_bf16(w2[n][0], hf0.b, oc, 0, 0, 0);
        oc = __builtin_amdgcn_mfma_f32_16x16x32_bf16(w2[n][1], hf1.b, oc, 0, 0, 0);
        oc = __builtin_amdgcn_mfma_f32_16x16x32_bf16(w2[n][2], hf2.b, oc, 0, 0, 0);
        oc = __builtin_amdgcn_mfma_f32_16x16x32_bf16(w2[n][3], hf3.b, oc, 0, 0, 0);
        *(f32x4*)(void*)(Wc + LDS_OUT + c * 144 + (16 * n + 4 * g) * 4) = oc;
    }
}

__device__ __forceinline__ void ph_store(char* Wc, int lane, float* outg) {
    f32x4 r0 = *(f32x4*)(void*)(Wc + LDS_OUT + (lane >> 2) * 144 + (lane & 3) * 32);
    f32x4 r1 = *(f32x4*)(void*)(Wc + LDS_OUT + (lane >> 2) * 144 + (lane & 3) * 32 + 16);
    *(f32x4*)(outg + lane * 8)     = r0;
    *(f32x4*)(outg + lane * 8 + 4) = r1;
}

// ---------------------------------------------------------------------------

__global__ __launch_bounds__(THREADS)
void block_mfma(const float* __restrict__ X,
                const float* __restrict__ Wattn,   // (4,32,24) d: k0..7 q8..15 v16..23
                const float* __restrict__ Wproj,   // (32,32) [in][out]
                const float* __restrict__ Wff1,    // (32,128)
                const float* __restrict__ Wff2,    // (128,32)
                float* __restrict__ Out,
                int ntiles)
{
    __shared__ __align__(16) char smem[4 * 2 * LDS_CTX];   // 61440 B

    const int lane = threadIdx.x & 63;
    const int wid  = threadIdx.x >> 6;
    const int g    = lane >> 4;   // k-group / C row-group
    const int c    = lane & 15;   // seq-row (col) for transposed GEMMs
    char* WA = smem + wid * (2 * LDS_CTX);
    char* WB = WA + LDS_CTX;

    // sqrt(32^-0.5 * log2(e)) folded into both K and Q weight columns
    const float wscale = 0.5050098f;

    // ---- resident weight fragments ----
    bf16x8 wqk[4], wv[2], wp[2], w1[8], w2[2][4];
    #pragma unroll
    for (int n = 0; n < 4; ++n)
        wqk[n] = gather_w(Wattn + n * 768 + c, 24, g, wscale);
    #pragma unroll
    for (int n = 0; n < 2; ++n) {
        int vch = 16 * n + c;
        wv[n] = gather_w(Wattn + (vch >> 3) * 768 + 16 + (vch & 7), 24, g, 1.f);
    }
    #pragma unroll
    for (int n = 0; n < 2; ++n)
        wp[n] = gather_w(Wproj + 16 * n + c, 32, g, 1.f);
    #pragma unroll
    for (int n = 0; n < 8; ++n)
        w1[n] = gather_w(Wff1 + 16 * n + c, 128, g, 1.f);
    #pragma unroll
    for (int n = 0; n < 2; ++n)
        #pragma unroll
        for (int ks = 0; ks < 4; ++ks)
            w2[n][ks] = gather_w(Wff2 + ks * 1024 + 16 * n + c, 32, g, 1.f);

    // ---- per-lane constant masks ----
    f32x4 mf;                                  // causal+same-seq mask (scores^T space)
    #pragma unroll
    for (int r = 0; r < 4; ++r) {
        int key = 4 * g + r;
        mf[r] = ((key >> 3) == (c >> 3) && (key & 7) <= (c & 7)) ? 1.f : 0.f;
    }
    const int b0 = (lane < 16) ? -1 : 0;                                   // zero k-groups g>0
    const int b1 = (((lane >> 3) & 1) == ((lane >> 5) & 1)) ? -1 : 0;      // PV block-diag
    const i32x4 mQK = {b0, b0, b0, b0};
    const i32x4 mPV = {b1, b1, b1, b1};

    const int tile0 = blockIdx.x * TPB + wid * TPW;
    if (tile0 >= ntiles) return;

    // ---- prefetch pair 0's X ----
    int p0 = tile0, p1 = (tile0 + 1 < ntiles) ? tile0 + 1 : ntiles - 1;
    f32x4 xaA = *(const f32x4*)(X + (size_t)p0 * 512 + lane * 8);
    f32x4 xbA = *(const f32x4*)(X + (size_t)p0 * 512 + lane * 8 + 4);
    f32x4 xaB = *(const f32x4*)(X + (size_t)p1 * 512 + lane * 8);
    f32x4 xbB = *(const f32x4*)(X + (size_t)p1 * 512 + lane * 8 + 4);

    #pragma unroll 1
    for (int it = 0; it < TPW; it += 2) {
        const int iA = tile0 + it;
        const int iB = tile0 + it + 1;
        const int ttA = (iA < ntiles) ? iA : ntiles - 1;   // clamped (recompute ok)
        const int ttB = (iB < ntiles) ? iB : ntiles - 1;
        const float* xgA = X + (size_t)ttA * 512;
        const float* xgB = X + (size_t)ttB * 512;

        // residuals at C^T points (consumed in proj; latency covered by P1-P3)
        f32x4 rxA0 = *(const f32x4*)(xgA + c * 32 + 4 * g);
        f32x4 rxA1 = *(const f32x4*)(xgA + c * 32 + 16 + 4 * g);
        f32x4 rxB0 = *(const f32x4*)(xgB + c * 32 + 4 * g);
        f32x4 rxB1 = *(const f32x4*)(xgB + c * 32 + 16 + 4 * g);

        ph_stage(WA, lane, xaA, xbA);
        ph_stage(WB, lane, xaB, xbB);

        // prefetch next pair's X (lands during this pair's compute)
        {
            int nA = (it + 2 < TPW && iA + 2 < ntiles) ? iA + 2 : ttA;
            int nB = (it + 3 < TPW && iB + 2 < ntiles) ? iB + 2 : ttB;
            xaA = *(const f32x4*)(X + (size_t)nA * 512 + lane * 8);
            xbA = *(const f32x4*)(X + (size_t)nA * 512 + lane * 8 + 4);
            xaB = *(const f32x4*)(X + (size_t)nB * 512 + lane * 8);
            xbB = *(const f32x4*)(X + (size_t)nB * 512 + lane * 8 + 4);
        }

        ph_qkv(WA, c, g, wqk, wv);
        ph_qkv(WB, c, g, wqk, wv);

        ph_scores(WA, c, g, mf, mQK);
        ph_scores(WB, c, g, mf, mQK);

        ph_pv(WA, c, g, mPV);
        ph_pv(WB, c, g, mPV);

        f32x4 x2A[2], x2B[2];
        ph_proj(WA, c, g, wp, rxA0, rxA1, x2A);
        ph_proj(WB, c, g, wp, rxB0, rxB1, x2B);

        ph_ff1(WA, c, g, w1);
        ph_ff1(WB, c, g, w1);

        ph_ff2(WA, c, g, w2, x2A);
        ph_ff2(WB, c, g, w2, x2B);

        if (iA < ntiles) ph_store(WA, lane, Out + (size_t)iA * 512);
        if (iB < ntiles) ph_store(WB, lane, Out + (size_t)iB * 512);
    }
}

extern "C" void kernel_launch(void* const* d_in, const int* in_sizes, int n_in,
                              void* d_out, int out_size, void* d_ws, size_t ws_size,
                              hipStream_t stream) {
    (void)n_in; (void)out_size; (void)d_ws; (void)ws_size;
    const float* X     = (const float*)d_in[0];
    const float* Wattn = (const float*)d_in[1];
    const float* Wproj = (const float*)d_in[2];
    const float* Wff1  = (const float*)d_in[3];
    const float* Wff2  = (const float*)d_in[4];
    float* Out = (float*)d_out;

    const int nseq   = in_sizes[0] / 256;   // (b, 8, 32)
    const int ntiles = nseq / 2;            // 16 rows per tile
    const int blocks = (ntiles + TPB - 1) / TPB;
    block_mfma<<<dim3(blocks), dim3(THREADS), 0, stream>>>(
        X, Wattn, Wproj, Wff1, Wff2, Out, ntiles);
}